// Round 9
// baseline (2745.325 us; speedup 1.0000x reference)
//
#include <hip/hip_runtime.h>
#include <math.h>

#define B_   4
#define N_   5440
#define D_   256
#define M_   21760          // B_*N_
#define NL_  6
#define MH_  10880          // M_/2

typedef unsigned short us16;
typedef unsigned int   u32;
typedef __attribute__((ext_vector_type(8))) short  short8v;
typedef __attribute__((ext_vector_type(4))) float  f32x4;

__device__ __forceinline__ float b2f(us16 u) {
  return __uint_as_float(((u32)u) << 16);
}
__device__ __forceinline__ int iclip(int v, int lo, int hi) {
  return v < lo ? lo : (v > hi ? hi : v);
}

// ---------------------------------------------------------------------------
// Weight prep: W [L][K][N] fp32 -> out rows [L][ld][2K] bf16 ([hi|lo] per row),
// column n of the matrix goes to row (rowOff + n) of the concat array.
// ---------------------------------------------------------------------------
__global__ __launch_bounds__(256) void split_wT(const float* __restrict__ W,
                                                us16* __restrict__ out,
                                                int K, int N, int ld, int rowOff) {
  const int idx = blockIdx.x * 256 + threadIdx.x;
  const int k = idx % K;
  const int n = (idx / K) % N;
  const int l = idx / (K * N);
  const float x = W[(size_t)l * K * N + (size_t)k * N + n];
  const u32 u = __float_as_uint(x);
  const us16 hi = (us16)(u >> 16);
  const float rem = x - __uint_as_float(u & 0xFFFF0000u);
  const us16 lo = (us16)(__float_as_uint(rem) >> 16);
  us16* o = out + (size_t)l * ld * 2 * K + (size_t)(rowOff + n) * 2 * K;
  o[k] = hi;
  o[K + k] = lo;
}

// ===========================================================================
// GEMM core: physical K loop (BK=64). Each tile stages A once
// (fp32 -> Ahi AND Alo in LDS) and B's hi+lo halves, then 3 MFMA passes:
//   acc += Ahi*Bhi + Ahi*Blo + Alo*Bhi   (fp32-grade split-bf16 product)
// LDS: 4 arrays of 128x72 us16 = 73.7 KB -> 2 blocks/CU.
// ===========================================================================

// ---------------------------------------------------------------------------
// Fused qkv GEMM (K=256): cols 0-255 val (fp32) | 256-511 off (bf16)
//                       | 512-639 attn logits (bf16)
// ---------------------------------------------------------------------------
__global__ __launch_bounds__(256) void gemm_qkv(
    const float* __restrict__ X, const float* __restrict__ P,
    const us16* __restrict__ BT,
    const float* __restrict__ bVal, const float* __restrict__ bOff,
    const float* __restrict__ bAttn,
    float* __restrict__ val, us16* __restrict__ off16,
    us16* __restrict__ attnl16) {
  __shared__ __align__(16) us16 Ah[128 * 72];
  __shared__ __align__(16) us16 Al[128 * 72];
  __shared__ __align__(16) us16 Bh[128 * 72];
  __shared__ __align__(16) us16 Bl[128 * 72];
  const int tid  = threadIdx.x;
  const int row0 = blockIdx.y * 128;
  const int col0 = blockIdx.x * 128;
  const bool useAdd = (col0 >= 256);
  const int l  = tid & 63;
  const int w  = tid >> 6;
  const int wr = (w >> 1) * 64;
  const int wc = (w & 1) * 64;
  const int lg = l >> 4;
  const int lr = l & 15;
  const int K = 256;

  f32x4 acc[4][4];
#pragma unroll
  for (int m = 0; m < 4; ++m)
#pragma unroll
    for (int n = 0; n < 4; ++n)
#pragma unroll
      for (int j = 0; j < 4; ++j) acc[m][n][j] = 0.f;

  for (int t = 0; t < 4; ++t) {
    const int kB = t << 6;
    __syncthreads();
    // ---- stage A: fp32 -> hi AND lo ----
#pragma unroll
    for (int r = 0; r < 4; ++r) {
      const int id = r * 256 + tid;
      const int row = id >> 3;
      const int cg = id & 7;
      const float* src = &X[(size_t)(row0 + row) * K + kB + cg * 8];
      float4 f0 = *(const float4*)src;
      float4 f1 = *(const float4*)(src + 4);
      if (useAdd) {
        const float* s2 = &P[(size_t)(row0 + row) * K + kB + cg * 8];
        float4 g0 = *(const float4*)s2;
        float4 g1 = *(const float4*)(s2 + 4);
        f0.x += g0.x; f0.y += g0.y; f0.z += g0.z; f0.w += g0.w;
        f1.x += g1.x; f1.y += g1.y; f1.z += g1.z; f1.w += g1.w;
      }
      const float xs[8] = {f0.x, f0.y, f0.z, f0.w, f1.x, f1.y, f1.z, f1.w};
      union { us16 u[8]; uint4 v; } ph, pl;
#pragma unroll
      for (int j = 0; j < 8; ++j) {
        const u32 u = __float_as_uint(xs[j]);
        ph.u[j] = (us16)(u >> 16);
        const float rem = xs[j] - __uint_as_float(u & 0xFFFF0000u);
        pl.u[j] = (us16)(__float_as_uint(rem) >> 16);
      }
      *(uint4*)&Ah[row * 72 + cg * 8] = ph.v;
      *(uint4*)&Al[row * 72 + cg * 8] = pl.v;
    }
    // ---- stage B: hi and lo halves of the 2K row ----
#pragma unroll
    for (int r = 0; r < 4; ++r) {
      const int id = r * 256 + tid;
      const int row = id >> 3;
      const int cg = id & 7;
      const us16* brow = &BT[(size_t)(col0 + row) * 512];
      *(uint4*)&Bh[row * 72 + cg * 8] = *(const uint4*)&brow[kB + cg * 8];
      *(uint4*)&Bl[row * 72 + cg * 8] = *(const uint4*)&brow[K + kB + cg * 8];
    }
    __syncthreads();
    // ---- 3 MFMA passes over this physical tile ----
#pragma unroll
    for (int kk = 0; kk < 2; ++kk) {
      const int ko = kk * 32 + lg * 8;
      short8v ah[4], bb[4], cc[4];
#pragma unroll
      for (int mf = 0; mf < 4; ++mf)
        ah[mf] = *(const short8v*)&Ah[(wr + mf * 16 + lr) * 72 + ko];
#pragma unroll
      for (int nf = 0; nf < 4; ++nf)
        bb[nf] = *(const short8v*)&Bh[(wc + nf * 16 + lr) * 72 + ko];
#pragma unroll
      for (int mf = 0; mf < 4; ++mf)
#pragma unroll
        for (int nf = 0; nf < 4; ++nf)
          acc[mf][nf] = __builtin_amdgcn_mfma_f32_16x16x32_bf16(ah[mf], bb[nf], acc[mf][nf], 0, 0, 0);
#pragma unroll
      for (int nf = 0; nf < 4; ++nf)
        cc[nf] = *(const short8v*)&Bl[(wc + nf * 16 + lr) * 72 + ko];
#pragma unroll
      for (int mf = 0; mf < 4; ++mf)
#pragma unroll
        for (int nf = 0; nf < 4; ++nf)
          acc[mf][nf] = __builtin_amdgcn_mfma_f32_16x16x32_bf16(ah[mf], cc[nf], acc[mf][nf], 0, 0, 0);
#pragma unroll
      for (int mf = 0; mf < 4; ++mf)
        ah[mf] = *(const short8v*)&Al[(wr + mf * 16 + lr) * 72 + ko];
#pragma unroll
      for (int mf = 0; mf < 4; ++mf)
#pragma unroll
        for (int nf = 0; nf < 4; ++nf)
          acc[mf][nf] = __builtin_amdgcn_mfma_f32_16x16x32_bf16(ah[mf], bb[nf], acc[mf][nf], 0, 0, 0);
    }
  }
  // ---- epilogue: block-uniform target select ----
  float* Cf = nullptr; us16* Ch = nullptr;
  const float* bp; int ldc, csub;
  if (col0 < 256)      { Cf = val;     bp = bVal;  ldc = 256; csub = 0;   }
  else if (col0 < 512) { Ch = off16;   bp = bOff;  ldc = 256; csub = 256; }
  else                 { Ch = attnl16; bp = bAttn; ldc = 128; csub = 512; }
#pragma unroll
  for (int mf = 0; mf < 4; ++mf) {
#pragma unroll
    for (int nf = 0; nf < 4; ++nf) {
      const int cc2 = col0 + wc + nf * 16 + lr - csub;
      const float bvv = bp[cc2];
#pragma unroll
      for (int j = 0; j < 4; ++j) {
        const int row = row0 + wr + mf * 16 + lg * 4 + j;
        const float v = acc[mf][nf][j] + bvv;
        if (Ch) Ch[(size_t)row * ldc + cc2] = (us16)(__float_as_uint(v) >> 16);
        else    Cf[(size_t)row * ldc + cc2] = v;
      }
    }
  }
}

// ---------------------------------------------------------------------------
// Generic split-bf16 GEMM with optional split-K via blockIdx.z:
//   z=0 -> C0 with bias; z=1 -> C1 without bias (partials summed later).
// ---------------------------------------------------------------------------
__global__ __launch_bounds__(256) void gemm_split(
    const float* __restrict__ A,
    const us16* __restrict__ BT, const float* __restrict__ bias,
    float* __restrict__ C0, float* __restrict__ C1,
    int Kfull, int kLen, int N, int relu) {
  __shared__ __align__(16) us16 Ah[128 * 72];
  __shared__ __align__(16) us16 Al[128 * 72];
  __shared__ __align__(16) us16 Bh[128 * 72];
  __shared__ __align__(16) us16 Bl[128 * 72];
  const int tid  = threadIdx.x;
  const int row0 = blockIdx.y * 128;
  const int col0 = blockIdx.x * 128;
  const int kOff = blockIdx.z * kLen;
  const int l  = tid & 63;
  const int w  = tid >> 6;
  const int wr = (w >> 1) * 64;
  const int wc = (w & 1) * 64;
  const int lg = l >> 4;
  const int lr = l & 15;

  f32x4 acc[4][4];
#pragma unroll
  for (int m = 0; m < 4; ++m)
#pragma unroll
    for (int n = 0; n < 4; ++n)
#pragma unroll
      for (int j = 0; j < 4; ++j) acc[m][n][j] = 0.f;

  const int T = kLen >> 6;
  for (int t = 0; t < T; ++t) {
    const int kB = kOff + (t << 6);
    __syncthreads();
#pragma unroll
    for (int r = 0; r < 4; ++r) {
      const int id = r * 256 + tid;
      const int row = id >> 3;
      const int cg = id & 7;
      const float* src = &A[(size_t)(row0 + row) * Kfull + kB + cg * 8];
      const float4 f0 = *(const float4*)src;
      const float4 f1 = *(const float4*)(src + 4);
      const float xs[8] = {f0.x, f0.y, f0.z, f0.w, f1.x, f1.y, f1.z, f1.w};
      union { us16 u[8]; uint4 v; } ph, pl;
#pragma unroll
      for (int j = 0; j < 8; ++j) {
        const u32 u = __float_as_uint(xs[j]);
        ph.u[j] = (us16)(u >> 16);
        const float rem = xs[j] - __uint_as_float(u & 0xFFFF0000u);
        pl.u[j] = (us16)(__float_as_uint(rem) >> 16);
      }
      *(uint4*)&Ah[row * 72 + cg * 8] = ph.v;
      *(uint4*)&Al[row * 72 + cg * 8] = pl.v;
    }
#pragma unroll
    for (int r = 0; r < 4; ++r) {
      const int id = r * 256 + tid;
      const int row = id >> 3;
      const int cg = id & 7;
      const us16* brow = &BT[(size_t)(col0 + row) * 2 * Kfull];
      *(uint4*)&Bh[row * 72 + cg * 8] = *(const uint4*)&brow[kB + cg * 8];
      *(uint4*)&Bl[row * 72 + cg * 8] = *(const uint4*)&brow[Kfull + kB + cg * 8];
    }
    __syncthreads();
#pragma unroll
    for (int kk = 0; kk < 2; ++kk) {
      const int ko = kk * 32 + lg * 8;
      short8v ah[4], bb[4], cc[4];
#pragma unroll
      for (int mf = 0; mf < 4; ++mf)
        ah[mf] = *(const short8v*)&Ah[(wr + mf * 16 + lr) * 72 + ko];
#pragma unroll
      for (int nf = 0; nf < 4; ++nf)
        bb[nf] = *(const short8v*)&Bh[(wc + nf * 16 + lr) * 72 + ko];
#pragma unroll
      for (int mf = 0; mf < 4; ++mf)
#pragma unroll
        for (int nf = 0; nf < 4; ++nf)
          acc[mf][nf] = __builtin_amdgcn_mfma_f32_16x16x32_bf16(ah[mf], bb[nf], acc[mf][nf], 0, 0, 0);
#pragma unroll
      for (int nf = 0; nf < 4; ++nf)
        cc[nf] = *(const short8v*)&Bl[(wc + nf * 16 + lr) * 72 + ko];
#pragma unroll
      for (int mf = 0; mf < 4; ++mf)
#pragma unroll
        for (int nf = 0; nf < 4; ++nf)
          acc[mf][nf] = __builtin_amdgcn_mfma_f32_16x16x32_bf16(ah[mf], cc[nf], acc[mf][nf], 0, 0, 0);
#pragma unroll
      for (int mf = 0; mf < 4; ++mf)
        ah[mf] = *(const short8v*)&Al[(wr + mf * 16 + lr) * 72 + ko];
#pragma unroll
      for (int mf = 0; mf < 4; ++mf)
#pragma unroll
        for (int nf = 0; nf < 4; ++nf)
          acc[mf][nf] = __builtin_amdgcn_mfma_f32_16x16x32_bf16(ah[mf], bb[nf], acc[mf][nf], 0, 0, 0);
    }
  }
  float* out = blockIdx.z ? C1 : C0;
  const float* bp = blockIdx.z ? nullptr : bias;
#pragma unroll
  for (int mf = 0; mf < 4; ++mf) {
#pragma unroll
    for (int nf = 0; nf < 4; ++nf) {
      const int col = col0 + wc + nf * 16 + lr;
      const float bvv = bp ? bp[col] : 0.f;
#pragma unroll
      for (int j = 0; j < 4; ++j) {
        const int row = row0 + wr + mf * 16 + lg * 4 + j;
        float v = acc[mf][nf][j] + bvv;
        if (relu) v = fmaxf(v, 0.f);
        out[(size_t)row * N + col] = v;
      }
    }
  }
}

// ---------------------------------------------------------------------------
// dst += src (float4)
// ---------------------------------------------------------------------------
__global__ __launch_bounds__(256) void add_into(float* __restrict__ dst,
                                                const float* __restrict__ src,
                                                int n4) {
  const int i = blockIdx.x * 256 + threadIdx.x;
  if (i < n4) {
    float4 d = ((float4*)dst)[i];
    const float4 s = ((const float4*)src)[i];
    d.x += s.x; d.y += s.y; d.z += s.z; d.w += s.w;
    ((float4*)dst)[i] = d;
  }
}

// ---------------------------------------------------------------------------
// MSDA fused softmax + bilinear sampling, point-parallel phase 1 +
// point-half/channel-pair phase 2 (float2 gathers, lanes 0-15: points 0-7,
// lanes 16-31: points 8-15, each lane covers channels {2c,2c+1}).
// Chunked XCD swizzle on blockIdx for val L2 locality (M_ % 8 == 0).
// ---------------------------------------------------------------------------
__global__ __launch_bounds__(256) void msda_sample(const us16* __restrict__ off,
                                                   const us16* __restrict__ attnl,
                                                   const float* __restrict__ val,
                                                   const float* __restrict__ vr,
                                                   float* __restrict__ samp) {
  __shared__ __align__(16) float sw[8][16][4];
  __shared__ __align__(16) int   srow[8][16][4];
  const int lsi[4] = {0, 4096, 5120, 5376};
  const int g    = threadIdx.x >> 5;
  const int lane = threadIdx.x & 31;
  const int bid  = blockIdx.x;
  const int sbid = (bid & 7) * (M_ / 8) + (bid >> 3);   // chunked XCD swizzle
  const int gid  = sbid * 8 + g;
  const int h  = gid & 7;
  const int bq = gid >> 3;
  const int q  = bq % N_;
  const int b  = bq / N_;

  const int lq = (q < 4096) ? 0 : ((q < 5120) ? 1 : ((q < 5376) ? 2 : 3));
  const int qq = q - lsi[lq];
  const int Wq = 64 >> lq;
  const int rq = qq >> (6 - lq);
  const int cq = qq & (Wq - 1);

  const float* vb = vr + b * 8;
  const float rxb = (cq + 0.5f) / (vb[lq * 2 + 0] * (float)Wq);
  const float ryb = (rq + 0.5f) / (vb[lq * 2 + 1] * (float)Wq);

  // ---- phase 1: point-parallel (p = lane&15; both halves duplicate) ----
  const int p = lane & 15;
  float lgt = b2f(attnl[(size_t)bq * 128 + h * 16 + p]);
  float mx = lgt;
#pragma unroll
  for (int m = 1; m < 16; m <<= 1) mx = fmaxf(mx, __shfl_xor(mx, m, 16));
  const float e = __expf(lgt - mx);
  float s = e;
#pragma unroll
  for (int m = 1; m < 16; m <<= 1) s += __shfl_xor(s, m, 16);
  const float aw = e / s;

  const us16* ob = off + (size_t)bq * 256 + h * 32;
  const float ox = b2f(ob[2 * p]);
  const float oy = b2f(ob[2 * p + 1]);
  const int lvl = p >> 2;
  const int Wl = 64 >> lvl;
  const float refx = rxb * vb[lvl * 2 + 0];
  const float refy = ryb * vb[lvl * 2 + 1];
  const float px = refx * (float)Wl + ox - 0.5f;
  const float py = refy * (float)Wl + oy - 0.5f;
  const float x0f = floorf(px), y0f = floorf(py);
  const float fx = px - x0f, fy = py - y0f;
  const int x0 = (int)x0f, y0 = (int)y0f;
  const int x1 = x0 + 1, y1 = y0 + 1;
  const bool vx0 = (x0 >= 0) & (x0 < Wl);
  const bool vx1 = (x1 >= 0) & (x1 < Wl);
  const bool vy0 = (y0 >= 0) & (y0 < Wl);
  const bool vy1 = (y1 >= 0) & (y1 < Wl);
  float w00 = (1.f - fx) * (1.f - fy) * aw; if (!(vx0 & vy0)) w00 = 0.f;
  float w10 = fx * (1.f - fy) * aw;         if (!(vx1 & vy0)) w10 = 0.f;
  float w01 = (1.f - fx) * fy * aw;         if (!(vx0 & vy1)) w01 = 0.f;
  float w11 = fx * fy * aw;                 if (!(vx1 & vy1)) w11 = 0.f;
  const int xc0 = iclip(x0, 0, Wl - 1), xc1 = iclip(x1, 0, Wl - 1);
  const int yc0 = iclip(y0, 0, Wl - 1), yc1 = iclip(y1, 0, Wl - 1);
  const int rowb = b * N_ + lsi[lvl];
  if (lane < 16) {
    *(float4*)&sw[g][p][0]  = make_float4(w00, w10, w01, w11);
    *(int4*)&srow[g][p][0]  = make_int4(rowb + yc0 * Wl + xc0,
                                        rowb + yc0 * Wl + xc1,
                                        rowb + yc1 * Wl + xc0,
                                        rowb + yc1 * Wl + xc1);
  }
  // ---- phase 2: point-half x channel-pair (float2 gathers) ----
  const int c2 = lane & 15;     // channel pair -> channels {2c2, 2c2+1}
  const int phh = lane >> 4;    // 0: points 0-7, 1: points 8-15
  const float* vcol = val + h * 32 + 2 * c2;
  float ax = 0.f, ay = 0.f;
#pragma unroll
  for (int k = 0; k < 8; ++k) {
    const int pp = phh * 8 + k;
    const float4 wv = *(const float4*)&sw[g][pp][0];
    const int4   rv = *(const int4*)&srow[g][pp][0];
    float2 v;
    v = *(const float2*)&vcol[(size_t)rv.x * 256]; ax += wv.x * v.x; ay += wv.x * v.y;
    v = *(const float2*)&vcol[(size_t)rv.y * 256]; ax += wv.y * v.x; ay += wv.y * v.y;
    v = *(const float2*)&vcol[(size_t)rv.z * 256]; ax += wv.z * v.x; ay += wv.z * v.y;
    v = *(const float2*)&vcol[(size_t)rv.w * 256]; ax += wv.w * v.x; ay += wv.w * v.y;
  }
  // merge the two point-halves (partner lane has same c2, other half)
  ax += __shfl_xor(ax, 16, 32);
  ay += __shfl_xor(ay, 16, 32);
  if (lane < 16) {
    float2 o2; o2.x = ax; o2.y = ay;
    *(float2*)&samp[(size_t)bq * 256 + h * 32 + 2 * c2] = o2;
  }
}

// ---------------------------------------------------------------------------
// out = LayerNorm(x + y) * g + be  (one 256-thread block per row)
// ---------------------------------------------------------------------------
__global__ __launch_bounds__(256) void resid_ln(const float* __restrict__ x,
                                                const float* __restrict__ y,
                                                const float* __restrict__ g,
                                                const float* __restrict__ be,
                                                float* __restrict__ out) {
  __shared__ float red[8];
  const int row = blockIdx.x;
  const int t = threadIdx.x;
  const size_t idx = (size_t)row * 256 + t;
  const float v = x[idx] + y[idx];

  float s = v;
#pragma unroll
  for (int o = 1; o < 64; o <<= 1) s += __shfl_xor(s, o, 64);
  const int wid = t >> 6;
  if ((t & 63) == 0) red[wid] = s;
  __syncthreads();
  const float mean = (red[0] + red[1] + red[2] + red[3]) * (1.f / 256.f);
  const float d = v - mean;
  float s2 = d * d;
#pragma unroll
  for (int o = 1; o < 64; o <<= 1) s2 += __shfl_xor(s2, o, 64);
  if ((t & 63) == 0) red[4 + wid] = s2;
  __syncthreads();
  const float var = (red[4] + red[5] + red[6] + red[7]) * (1.f / 256.f);
  out[idx] = d * rsqrtf(var + 1e-5f) * g[t] + be[t];
}

// ---------------------------------------------------------------------------
extern "C" void kernel_launch(void* const* d_in, const int* in_sizes, int n_in,
                              void* d_out, int out_size, void* d_ws, size_t ws_size,
                              hipStream_t stream) {
  const float* src    = (const float*)d_in[0];
  const float* pos    = (const float*)d_in[1];
  const float* vr     = (const float*)d_in[2];
  const float* W_off  = (const float*)d_in[5];
  const float* b_off  = (const float*)d_in[6];
  const float* W_attn = (const float*)d_in[7];
  const float* b_attn = (const float*)d_in[8];
  const float* W_val  = (const float*)d_in[9];
  const float* b_val  = (const float*)d_in[10];
  const float* W_out  = (const float*)d_in[11];
  const float* b_out  = (const float*)d_in[12];
  const float* g1     = (const float*)d_in[13];
  const float* be1    = (const float*)d_in[14];
  const float* W1     = (const float*)d_in[15];
  const float* bl1    = (const float*)d_in[16];
  const float* W2     = (const float*)d_in[17];
  const float* bl2    = (const float*)d_in[18];
  const float* g2     = (const float*)d_in[19];
  const float* be2    = (const float*)d_in[20];

  const size_t XD = (size_t)M_ * 256;
  float* ws = (float*)d_ws;
  float* x  = ws;                       // persistent activation
  float* y  = ws + XD;                  // GEMM fp32 output
  float* R  = ws + 2 * XD;              // union region (M_*704 floats)
  us16*  off16   = (us16*)R;                         // M*256 us16
  us16*  attnl16 = (us16*)(R + (size_t)M_ * 128);    // M*128 us16
  float* val     = R + (size_t)M_ * 192;             // M*256 fl
  float* samp    = R + (size_t)M_ * 448;             // M*256 fl
  float* hbuf    = R;                                // MH_*1024 fl = M*512 fl
  float* y2      = R + (size_t)M_ * 512;             // MH_*256 fl = M*128 fl
  us16*  wreg    = (us16*)(R + (size_t)M_ * 704);    // split weights (18.1 MB)
  us16* wCat  = wreg;                    // 6 * 640*512 (val|off|attn concat)
  us16* wOut  = wCat + 6 * 327680;       // 6 * 256*512
  us16* w1s   = wOut + 6 * 131072;       // 6 * 1024*512
  us16* w2s   = w1s  + 6 * 524288;       // 6 * 256*2048

  const dim3 blk(256);
  // ---- weight prep (once per launch) ----
  split_wT<<<6 * 256 * 256 / 256, blk, 0, stream>>>(W_val,  wCat, 256, 256, 640, 0);
  split_wT<<<6 * 256 * 256 / 256, blk, 0, stream>>>(W_off,  wCat, 256, 256, 640, 256);
  split_wT<<<6 * 256 * 128 / 256, blk, 0, stream>>>(W_attn, wCat, 256, 128, 640, 512);
  split_wT<<<6 * 256 * 256 / 256, blk, 0, stream>>>(W_out,  wOut, 256, 256, 256, 0);
  split_wT<<<6 * 256 * 1024 / 256, blk, 0, stream>>>(W1,    w1s,  256, 1024, 1024, 0);
  split_wT<<<6 * 1024 * 256 / 256, blk, 0, stream>>>(W2,    w2s,  1024, 256, 256, 0);

  const float* xc = src;
  for (int i = 0; i < NL_; ++i) {
    // fused: val (x@Wval, fp32) | off ((x+pos)@Woff, bf16) | attnl (bf16)
    gemm_qkv<<<dim3(5, 170), blk, 0, stream>>>(
        xc, pos, wCat + (size_t)i * 327680,
        b_val + i * 256, b_off + i * 256, b_attn + i * 128,
        val, off16, attnl16);
    // fused softmax + bilinear sampling
    msda_sample<<<M_, blk, 0, stream>>>(off16, attnl16, val, vr, samp);
    // y = samp @ W_out
    gemm_split<<<dim3(2, 170, 1), blk, 0, stream>>>(
        samp, wOut + (size_t)i * 131072, b_out + i * 256, y, nullptr,
        256, 256, 256, 0);
    // x = LN(x + y)
    resid_ln<<<M_, blk, 0, stream>>>(xc, y, g1 + i * 256, be1 + i * 256, x);
    // FFN in two M-halves; W2 split-K=2 (z=0 -> y, z=1 -> y2, then merge)
    for (int half = 0; half < 2; ++half) {
      const size_t ro = (size_t)half * MH_;
      gemm_split<<<dim3(8, 85, 1), blk, 0, stream>>>(
          x + ro * 256, w1s + (size_t)i * 524288, bl1 + i * 1024,
          hbuf, nullptr, 256, 256, 1024, 1);
      gemm_split<<<dim3(2, 85, 2), blk, 0, stream>>>(
          hbuf, w2s + (size_t)i * 524288, bl2 + i * 256,
          y + ro * 256, y2, 1024, 512, 256, 0);
      add_into<<<(MH_ * 64 + 255) / 256, blk, 0, stream>>>(
          y + ro * 256, y2, MH_ * 64);
    }
    // x = LN(x + y)  (last layer -> d_out)
    float* dst = (i == NL_ - 1) ? (float*)d_out : x;
    resid_ln<<<M_, blk, 0, stream>>>(x, y, g2 + i * 256, be2 + i * 256, dst);
    xc = x;
  }
}

// Round 10
// 2444.383 us; speedup vs baseline: 1.1231x; 1.1231x over previous
//
#include <hip/hip_runtime.h>
#include <math.h>

#define B_   4
#define N_   5440
#define D_   256
#define M_   21760          // B_*N_
#define NL_  6
#define MH_  10880          // M_/2

typedef unsigned short us16;
typedef unsigned int   u32;
typedef __attribute__((ext_vector_type(8))) short  short8v;
typedef __attribute__((ext_vector_type(4))) float  f32x4;

__device__ __forceinline__ float b2f(us16 u) {
  return __uint_as_float(((u32)u) << 16);
}
__device__ __forceinline__ int iclip(int v, int lo, int hi) {
  return v < lo ? lo : (v > hi ? hi : v);
}

// ---------------------------------------------------------------------------
// Weight prep: W [L][K][N] fp32 -> out rows [L][ld][2K] bf16 ([hi|lo] per row),
// column n of the matrix goes to row (rowOff + n) of the concat array.
// ---------------------------------------------------------------------------
__global__ __launch_bounds__(256) void split_wT(const float* __restrict__ W,
                                                us16* __restrict__ out,
                                                int K, int N, int ld, int rowOff) {
  const int idx = blockIdx.x * 256 + threadIdx.x;
  const int k = idx % K;
  const int n = (idx / K) % N;
  const int l = idx / (K * N);
  const float x = W[(size_t)l * K * N + (size_t)k * N + n];
  const u32 u = __float_as_uint(x);
  const us16 hi = (us16)(u >> 16);
  const float rem = x - __uint_as_float(u & 0xFFFF0000u);
  const us16 lo = (us16)(__float_as_uint(rem) >> 16);
  us16* o = out + (size_t)l * ld * 2 * K + (size_t)(rowOff + n) * 2 * K;
  o[k] = hi;
  o[K + k] = lo;
}

// ===========================================================================
// GEMM core: physical K loop (BK=64). Each tile stages A once
// (fp32 -> Ahi AND Alo in LDS) and B's hi+lo halves, then 3 MFMA passes:
//   acc += Ahi*Bhi + Ahi*Blo + Alo*Bhi   (fp32-grade split-bf16 product)
// LDS: 4 arrays of 128x72 us16 = 73.7 KB -> 2 blocks/CU.
// ===========================================================================

// ---------------------------------------------------------------------------
// Fused qkv GEMM (K=256): cols 0-255 val (fp32) | 256-511 off (bf16)
//                       | 512-639 attn logits (bf16)
// ---------------------------------------------------------------------------
__global__ __launch_bounds__(256) void gemm_qkv(
    const float* __restrict__ X, const float* __restrict__ P,
    const us16* __restrict__ BT,
    const float* __restrict__ bVal, const float* __restrict__ bOff,
    const float* __restrict__ bAttn,
    float* __restrict__ val, us16* __restrict__ off16,
    us16* __restrict__ attnl16) {
  __shared__ __align__(16) us16 Ah[128 * 72];
  __shared__ __align__(16) us16 Al[128 * 72];
  __shared__ __align__(16) us16 Bh[128 * 72];
  __shared__ __align__(16) us16 Bl[128 * 72];
  const int tid  = threadIdx.x;
  const int row0 = blockIdx.y * 128;
  const int col0 = blockIdx.x * 128;
  const bool useAdd = (col0 >= 256);
  const int l  = tid & 63;
  const int w  = tid >> 6;
  const int wr = (w >> 1) * 64;
  const int wc = (w & 1) * 64;
  const int lg = l >> 4;
  const int lr = l & 15;
  const int K = 256;

  f32x4 acc[4][4];
#pragma unroll
  for (int m = 0; m < 4; ++m)
#pragma unroll
    for (int n = 0; n < 4; ++n)
#pragma unroll
      for (int j = 0; j < 4; ++j) acc[m][n][j] = 0.f;

  for (int t = 0; t < 4; ++t) {
    const int kB = t << 6;
    __syncthreads();
    // ---- stage A: fp32 -> hi AND lo ----
#pragma unroll
    for (int r = 0; r < 4; ++r) {
      const int id = r * 256 + tid;
      const int row = id >> 3;
      const int cg = id & 7;
      const float* src = &X[(size_t)(row0 + row) * K + kB + cg * 8];
      float4 f0 = *(const float4*)src;
      float4 f1 = *(const float4*)(src + 4);
      if (useAdd) {
        const float* s2 = &P[(size_t)(row0 + row) * K + kB + cg * 8];
        float4 g0 = *(const float4*)s2;
        float4 g1 = *(const float4*)(s2 + 4);
        f0.x += g0.x; f0.y += g0.y; f0.z += g0.z; f0.w += g0.w;
        f1.x += g1.x; f1.y += g1.y; f1.z += g1.z; f1.w += g1.w;
      }
      const float xs[8] = {f0.x, f0.y, f0.z, f0.w, f1.x, f1.y, f1.z, f1.w};
      union { us16 u[8]; uint4 v; } ph, pl;
#pragma unroll
      for (int j = 0; j < 8; ++j) {
        const u32 u = __float_as_uint(xs[j]);
        ph.u[j] = (us16)(u >> 16);
        const float rem = xs[j] - __uint_as_float(u & 0xFFFF0000u);
        pl.u[j] = (us16)(__float_as_uint(rem) >> 16);
      }
      *(uint4*)&Ah[row * 72 + cg * 8] = ph.v;
      *(uint4*)&Al[row * 72 + cg * 8] = pl.v;
    }
    // ---- stage B: hi and lo halves of the 2K row ----
#pragma unroll
    for (int r = 0; r < 4; ++r) {
      const int id = r * 256 + tid;
      const int row = id >> 3;
      const int cg = id & 7;
      const us16* brow = &BT[(size_t)(col0 + row) * 512];
      *(uint4*)&Bh[row * 72 + cg * 8] = *(const uint4*)&brow[kB + cg * 8];
      *(uint4*)&Bl[row * 72 + cg * 8] = *(const uint4*)&brow[K + kB + cg * 8];
    }
    __syncthreads();
    // ---- 3 MFMA passes over this physical tile ----
#pragma unroll
    for (int kk = 0; kk < 2; ++kk) {
      const int ko = kk * 32 + lg * 8;
      short8v ah[4], bb[4], cc[4];
#pragma unroll
      for (int mf = 0; mf < 4; ++mf)
        ah[mf] = *(const short8v*)&Ah[(wr + mf * 16 + lr) * 72 + ko];
#pragma unroll
      for (int nf = 0; nf < 4; ++nf)
        bb[nf] = *(const short8v*)&Bh[(wc + nf * 16 + lr) * 72 + ko];
#pragma unroll
      for (int mf = 0; mf < 4; ++mf)
#pragma unroll
        for (int nf = 0; nf < 4; ++nf)
          acc[mf][nf] = __builtin_amdgcn_mfma_f32_16x16x32_bf16(ah[mf], bb[nf], acc[mf][nf], 0, 0, 0);
#pragma unroll
      for (int nf = 0; nf < 4; ++nf)
        cc[nf] = *(const short8v*)&Bl[(wc + nf * 16 + lr) * 72 + ko];
#pragma unroll
      for (int mf = 0; mf < 4; ++mf)
#pragma unroll
        for (int nf = 0; nf < 4; ++nf)
          acc[mf][nf] = __builtin_amdgcn_mfma_f32_16x16x32_bf16(ah[mf], cc[nf], acc[mf][nf], 0, 0, 0);
#pragma unroll
      for (int mf = 0; mf < 4; ++mf)
        ah[mf] = *(const short8v*)&Al[(wr + mf * 16 + lr) * 72 + ko];
#pragma unroll
      for (int mf = 0; mf < 4; ++mf)
#pragma unroll
        for (int nf = 0; nf < 4; ++nf)
          acc[mf][nf] = __builtin_amdgcn_mfma_f32_16x16x32_bf16(ah[mf], bb[nf], acc[mf][nf], 0, 0, 0);
    }
  }
  // ---- epilogue: block-uniform target select ----
  float* Cf = nullptr; us16* Ch = nullptr;
  const float* bp; int ldc, csub;
  if (col0 < 256)      { Cf = val;     bp = bVal;  ldc = 256; csub = 0;   }
  else if (col0 < 512) { Ch = off16;   bp = bOff;  ldc = 256; csub = 256; }
  else                 { Ch = attnl16; bp = bAttn; ldc = 128; csub = 512; }
#pragma unroll
  for (int mf = 0; mf < 4; ++mf) {
#pragma unroll
    for (int nf = 0; nf < 4; ++nf) {
      const int cc2 = col0 + wc + nf * 16 + lr - csub;
      const float bvv = bp[cc2];
#pragma unroll
      for (int j = 0; j < 4; ++j) {
        const int row = row0 + wr + mf * 16 + lg * 4 + j;
        const float v = acc[mf][nf][j] + bvv;
        if (Ch) Ch[(size_t)row * ldc + cc2] = (us16)(__float_as_uint(v) >> 16);
        else    Cf[(size_t)row * ldc + cc2] = v;
      }
    }
  }
}

// ---------------------------------------------------------------------------
// Generic split-bf16 GEMM with optional split-K via blockIdx.z:
//   z=0 -> C0 with bias; z=1 -> C1 without bias (summed in resid_ln3).
// ---------------------------------------------------------------------------
__global__ __launch_bounds__(256) void gemm_split(
    const float* __restrict__ A,
    const us16* __restrict__ BT, const float* __restrict__ bias,
    float* __restrict__ C0, float* __restrict__ C1,
    int Kfull, int kLen, int N, int relu) {
  __shared__ __align__(16) us16 Ah[128 * 72];
  __shared__ __align__(16) us16 Al[128 * 72];
  __shared__ __align__(16) us16 Bh[128 * 72];
  __shared__ __align__(16) us16 Bl[128 * 72];
  const int tid  = threadIdx.x;
  const int row0 = blockIdx.y * 128;
  const int col0 = blockIdx.x * 128;
  const int kOff = blockIdx.z * kLen;
  const int l  = tid & 63;
  const int w  = tid >> 6;
  const int wr = (w >> 1) * 64;
  const int wc = (w & 1) * 64;
  const int lg = l >> 4;
  const int lr = l & 15;

  f32x4 acc[4][4];
#pragma unroll
  for (int m = 0; m < 4; ++m)
#pragma unroll
    for (int n = 0; n < 4; ++n)
#pragma unroll
      for (int j = 0; j < 4; ++j) acc[m][n][j] = 0.f;

  const int T = kLen >> 6;
  for (int t = 0; t < T; ++t) {
    const int kB = kOff + (t << 6);
    __syncthreads();
#pragma unroll
    for (int r = 0; r < 4; ++r) {
      const int id = r * 256 + tid;
      const int row = id >> 3;
      const int cg = id & 7;
      const float* src = &A[(size_t)(row0 + row) * Kfull + kB + cg * 8];
      const float4 f0 = *(const float4*)src;
      const float4 f1 = *(const float4*)(src + 4);
      const float xs[8] = {f0.x, f0.y, f0.z, f0.w, f1.x, f1.y, f1.z, f1.w};
      union { us16 u[8]; uint4 v; } ph, pl;
#pragma unroll
      for (int j = 0; j < 8; ++j) {
        const u32 u = __float_as_uint(xs[j]);
        ph.u[j] = (us16)(u >> 16);
        const float rem = xs[j] - __uint_as_float(u & 0xFFFF0000u);
        pl.u[j] = (us16)(__float_as_uint(rem) >> 16);
      }
      *(uint4*)&Ah[row * 72 + cg * 8] = ph.v;
      *(uint4*)&Al[row * 72 + cg * 8] = pl.v;
    }
#pragma unroll
    for (int r = 0; r < 4; ++r) {
      const int id = r * 256 + tid;
      const int row = id >> 3;
      const int cg = id & 7;
      const us16* brow = &BT[(size_t)(col0 + row) * 2 * Kfull];
      *(uint4*)&Bh[row * 72 + cg * 8] = *(const uint4*)&brow[kB + cg * 8];
      *(uint4*)&Bl[row * 72 + cg * 8] = *(const uint4*)&brow[Kfull + kB + cg * 8];
    }
    __syncthreads();
#pragma unroll
    for (int kk = 0; kk < 2; ++kk) {
      const int ko = kk * 32 + lg * 8;
      short8v ah[4], bb[4], cc[4];
#pragma unroll
      for (int mf = 0; mf < 4; ++mf)
        ah[mf] = *(const short8v*)&Ah[(wr + mf * 16 + lr) * 72 + ko];
#pragma unroll
      for (int nf = 0; nf < 4; ++nf)
        bb[nf] = *(const short8v*)&Bh[(wc + nf * 16 + lr) * 72 + ko];
#pragma unroll
      for (int mf = 0; mf < 4; ++mf)
#pragma unroll
        for (int nf = 0; nf < 4; ++nf)
          acc[mf][nf] = __builtin_amdgcn_mfma_f32_16x16x32_bf16(ah[mf], bb[nf], acc[mf][nf], 0, 0, 0);
#pragma unroll
      for (int nf = 0; nf < 4; ++nf)
        cc[nf] = *(const short8v*)&Bl[(wc + nf * 16 + lr) * 72 + ko];
#pragma unroll
      for (int mf = 0; mf < 4; ++mf)
#pragma unroll
        for (int nf = 0; nf < 4; ++nf)
          acc[mf][nf] = __builtin_amdgcn_mfma_f32_16x16x32_bf16(ah[mf], cc[nf], acc[mf][nf], 0, 0, 0);
#pragma unroll
      for (int mf = 0; mf < 4; ++mf)
        ah[mf] = *(const short8v*)&Al[(wr + mf * 16 + lr) * 72 + ko];
#pragma unroll
      for (int mf = 0; mf < 4; ++mf)
#pragma unroll
        for (int nf = 0; nf < 4; ++nf)
          acc[mf][nf] = __builtin_amdgcn_mfma_f32_16x16x32_bf16(ah[mf], bb[nf], acc[mf][nf], 0, 0, 0);
    }
  }
  float* out = blockIdx.z ? C1 : C0;
  const float* bp = blockIdx.z ? nullptr : bias;
#pragma unroll
  for (int mf = 0; mf < 4; ++mf) {
#pragma unroll
    for (int nf = 0; nf < 4; ++nf) {
      const int col = col0 + wc + nf * 16 + lr;
      const float bvv = bp ? bp[col] : 0.f;
#pragma unroll
      for (int j = 0; j < 4; ++j) {
        const int row = row0 + wr + mf * 16 + lg * 4 + j;
        float v = acc[mf][nf][j] + bvv;
        if (relu) v = fmaxf(v, 0.f);
        out[(size_t)row * N + col] = v;
      }
    }
  }
}

// ---------------------------------------------------------------------------
// MSDA fused softmax + bilinear sampling, point-parallel (round-8 verified:
// 79 us). Phase 1: lane p computes point p's weights + clamped row indices;
// Phase 2: all 32 lanes (channels) replay 16 points via broadcast LDS reads.
// ---------------------------------------------------------------------------
__global__ __launch_bounds__(256) void msda_sample(const us16* __restrict__ off,
                                                   const us16* __restrict__ attnl,
                                                   const float* __restrict__ val,
                                                   const float* __restrict__ vr,
                                                   float* __restrict__ samp) {
  __shared__ __align__(16) float sw[8][16][4];
  __shared__ __align__(16) int   srow[8][16][4];
  const int lsi[4] = {0, 4096, 5120, 5376};
  const int g    = threadIdx.x >> 5;
  const int lane = threadIdx.x & 31;
  const int gid  = blockIdx.x * 8 + g;
  const int h  = gid & 7;
  const int bq = gid >> 3;
  const int q  = bq % N_;
  const int b  = bq / N_;

  const int lq = (q < 4096) ? 0 : ((q < 5120) ? 1 : ((q < 5376) ? 2 : 3));
  const int qq = q - lsi[lq];
  const int Wq = 64 >> lq;
  const int rq = qq >> (6 - lq);
  const int cq = qq & (Wq - 1);

  const float* vb = vr + b * 8;
  const float rxb = (cq + 0.5f) / (vb[lq * 2 + 0] * (float)Wq);
  const float ryb = (rq + 0.5f) / (vb[lq * 2 + 1] * (float)Wq);

  const int p = lane & 15;
  float lgt = b2f(attnl[(size_t)bq * 128 + h * 16 + p]);
  float mx = lgt;
#pragma unroll
  for (int m = 1; m < 16; m <<= 1) mx = fmaxf(mx, __shfl_xor(mx, m, 16));
  const float e = __expf(lgt - mx);
  float s = e;
#pragma unroll
  for (int m = 1; m < 16; m <<= 1) s += __shfl_xor(s, m, 16);
  const float aw = e / s;

  const us16* ob = off + (size_t)bq * 256 + h * 32;
  const float ox = b2f(ob[2 * p]);
  const float oy = b2f(ob[2 * p + 1]);
  const int lvl = p >> 2;
  const int Wl = 64 >> lvl;
  const float refx = rxb * vb[lvl * 2 + 0];
  const float refy = ryb * vb[lvl * 2 + 1];
  const float px = refx * (float)Wl + ox - 0.5f;
  const float py = refy * (float)Wl + oy - 0.5f;
  const float x0f = floorf(px), y0f = floorf(py);
  const float fx = px - x0f, fy = py - y0f;
  const int x0 = (int)x0f, y0 = (int)y0f;
  const int x1 = x0 + 1, y1 = y0 + 1;
  const bool vx0 = (x0 >= 0) & (x0 < Wl);
  const bool vx1 = (x1 >= 0) & (x1 < Wl);
  const bool vy0 = (y0 >= 0) & (y0 < Wl);
  const bool vy1 = (y1 >= 0) & (y1 < Wl);
  float w00 = (1.f - fx) * (1.f - fy) * aw; if (!(vx0 & vy0)) w00 = 0.f;
  float w10 = fx * (1.f - fy) * aw;         if (!(vx1 & vy0)) w10 = 0.f;
  float w01 = (1.f - fx) * fy * aw;         if (!(vx0 & vy1)) w01 = 0.f;
  float w11 = fx * fy * aw;                 if (!(vx1 & vy1)) w11 = 0.f;
  const int xc0 = iclip(x0, 0, Wl - 1), xc1 = iclip(x1, 0, Wl - 1);
  const int yc0 = iclip(y0, 0, Wl - 1), yc1 = iclip(y1, 0, Wl - 1);
  const int rowb = b * N_ + lsi[lvl];
  if (lane < 16) {
    *(float4*)&sw[g][p][0]  = make_float4(w00, w10, w01, w11);
    *(int4*)&srow[g][p][0]  = make_int4(rowb + yc0 * Wl + xc0,
                                        rowb + yc0 * Wl + xc1,
                                        rowb + yc1 * Wl + xc0,
                                        rowb + yc1 * Wl + xc1);
  }
  const float* vcol = val + h * 32 + lane;
  float acc = 0.f;
#pragma unroll
  for (int pp = 0; pp < 16; ++pp) {
    const float4 wv = *(const float4*)&sw[g][pp][0];
    const int4   rv = *(const int4*)&srow[g][pp][0];
    acc += wv.x * vcol[rv.x * 256];
    acc += wv.y * vcol[rv.y * 256];
    acc += wv.z * vcol[rv.z * 256];
    acc += wv.w * vcol[rv.w * 256];
  }
  samp[(size_t)bq * 256 + h * 32 + lane] = acc;
}

// ---------------------------------------------------------------------------
// out = LayerNorm(x + y) * g + be  (one 256-thread block per row)
// ---------------------------------------------------------------------------
__global__ __launch_bounds__(256) void resid_ln(const float* __restrict__ x,
                                                const float* __restrict__ y,
                                                const float* __restrict__ g,
                                                const float* __restrict__ be,
                                                float* __restrict__ out) {
  __shared__ float red[8];
  const int row = blockIdx.x;
  const int t = threadIdx.x;
  const size_t idx = (size_t)row * 256 + t;
  const float v = x[idx] + y[idx];

  float s = v;
#pragma unroll
  for (int o = 1; o < 64; o <<= 1) s += __shfl_xor(s, o, 64);
  const int wid = t >> 6;
  if ((t & 63) == 0) red[wid] = s;
  __syncthreads();
  const float mean = (red[0] + red[1] + red[2] + red[3]) * (1.f / 256.f);
  const float d = v - mean;
  float s2 = d * d;
#pragma unroll
  for (int o = 1; o < 64; o <<= 1) s2 += __shfl_xor(s2, o, 64);
  if ((t & 63) == 0) red[4 + wid] = s2;
  __syncthreads();
  const float var = (red[4] + red[5] + red[6] + red[7]) * (1.f / 256.f);
  out[idx] = d * rsqrtf(var + 1e-5f) * g[t] + be[t];
}

// ---------------------------------------------------------------------------
// out = LayerNorm(x + y + y2) * g + be  (3-term: folds split-K partial merge)
// Safe when out aliases y2 (per-thread read-before-write).
// ---------------------------------------------------------------------------
__global__ __launch_bounds__(256) void resid_ln3(const float* __restrict__ x,
                                                 const float* __restrict__ y,
                                                 const float* __restrict__ y2,
                                                 const float* __restrict__ g,
                                                 const float* __restrict__ be,
                                                 float* __restrict__ out) {
  __shared__ float red[8];
  const int row = blockIdx.x;
  const int t = threadIdx.x;
  const size_t idx = (size_t)row * 256 + t;
  const float v = x[idx] + y[idx] + y2[idx];

  float s = v;
#pragma unroll
  for (int o = 1; o < 64; o <<= 1) s += __shfl_xor(s, o, 64);
  const int wid = t >> 6;
  if ((t & 63) == 0) red[wid] = s;
  __syncthreads();
  const float mean = (red[0] + red[1] + red[2] + red[3]) * (1.f / 256.f);
  const float d = v - mean;
  float s2 = d * d;
#pragma unroll
  for (int o = 1; o < 64; o <<= 1) s2 += __shfl_xor(s2, o, 64);
  if ((t & 63) == 0) red[4 + wid] = s2;
  __syncthreads();
  const float var = (red[4] + red[5] + red[6] + red[7]) * (1.f / 256.f);
  out[idx] = d * rsqrtf(var + 1e-5f) * g[t] + be[t];
}

// ---------------------------------------------------------------------------
extern "C" void kernel_launch(void* const* d_in, const int* in_sizes, int n_in,
                              void* d_out, int out_size, void* d_ws, size_t ws_size,
                              hipStream_t stream) {
  const float* src    = (const float*)d_in[0];
  const float* pos    = (const float*)d_in[1];
  const float* vr     = (const float*)d_in[2];
  const float* W_off  = (const float*)d_in[5];
  const float* b_off  = (const float*)d_in[6];
  const float* W_attn = (const float*)d_in[7];
  const float* b_attn = (const float*)d_in[8];
  const float* W_val  = (const float*)d_in[9];
  const float* b_val  = (const float*)d_in[10];
  const float* W_out  = (const float*)d_in[11];
  const float* b_out  = (const float*)d_in[12];
  const float* g1     = (const float*)d_in[13];
  const float* be1    = (const float*)d_in[14];
  const float* W1     = (const float*)d_in[15];
  const float* bl1    = (const float*)d_in[16];
  const float* W2     = (const float*)d_in[17];
  const float* bl2    = (const float*)d_in[18];
  const float* g2     = (const float*)d_in[19];
  const float* be2    = (const float*)d_in[20];

  const size_t XD = (size_t)M_ * 256;
  float* ws = (float*)d_ws;
  float* x  = ws;                       // persistent activation
  float* y  = ws + XD;                  // GEMM fp32 output
  float* R  = ws + 2 * XD;              // union region (M_*704 floats)
  us16*  off16   = (us16*)R;                         // M*256 us16
  us16*  attnl16 = (us16*)(R + (size_t)M_ * 128);    // M*128 us16
  float* val     = R + (size_t)M_ * 192;             // M*256 fl
  float* samp    = R + (size_t)M_ * 448;             // M*256 fl
  float* hbuf    = R;                                // MH_*1024 fl = M*512 fl
  float* y2      = (float*)d_out;                    // full-M split-K partial
                                                     // (d_out dead until final LN)
  us16*  wreg    = (us16*)(R + (size_t)M_ * 704);    // split weights (18.1 MB)
  us16* wCat  = wreg;                    // 6 * 640*512 (val|off|attn concat)
  us16* wOut  = wCat + 6 * 327680;       // 6 * 256*512
  us16* w1s   = wOut + 6 * 131072;       // 6 * 1024*512
  us16* w2s   = w1s  + 6 * 524288;       // 6 * 256*2048

  const dim3 blk(256);
  // ---- weight prep (once per launch) ----
  split_wT<<<6 * 256 * 256 / 256, blk, 0, stream>>>(W_val,  wCat, 256, 256, 640, 0);
  split_wT<<<6 * 256 * 256 / 256, blk, 0, stream>>>(W_off,  wCat, 256, 256, 640, 256);
  split_wT<<<6 * 256 * 128 / 256, blk, 0, stream>>>(W_attn, wCat, 256, 128, 640, 512);
  split_wT<<<6 * 256 * 256 / 256, blk, 0, stream>>>(W_out,  wOut, 256, 256, 256, 0);
  split_wT<<<6 * 256 * 1024 / 256, blk, 0, stream>>>(W1,    w1s,  256, 1024, 1024, 0);
  split_wT<<<6 * 1024 * 256 / 256, blk, 0, stream>>>(W2,    w2s,  1024, 256, 256, 0);

  const float* xc = src;
  for (int i = 0; i < NL_; ++i) {
    // fused: val (x@Wval, fp32) | off ((x+pos)@Woff, bf16) | attnl (bf16)
    gemm_qkv<<<dim3(5, 170), blk, 0, stream>>>(
        xc, pos, wCat + (size_t)i * 327680,
        b_val + i * 256, b_off + i * 256, b_attn + i * 128,
        val, off16, attnl16);
    // fused softmax + bilinear sampling
    msda_sample<<<M_, blk, 0, stream>>>(off16, attnl16, val, vr, samp);
    // y = samp @ W_out
    gemm_split<<<dim3(2, 170, 1), blk, 0, stream>>>(
        samp, wOut + (size_t)i * 131072, b_out + i * 256, y, nullptr,
        256, 256, 256, 0);
    // x = LN(x + y)
    resid_ln<<<M_, blk, 0, stream>>>(xc, y, g1 + i * 256, be1 + i * 256, x);
    // FFN in two M-halves; W2 split-K=2: z=0 -> y (+bias), z=1 -> y2 (full-M)
    for (int half = 0; half < 2; ++half) {
      const size_t ro = (size_t)half * MH_;
      gemm_split<<<dim3(8, 85, 1), blk, 0, stream>>>(
          x + ro * 256, w1s + (size_t)i * 524288, bl1 + i * 1024,
          hbuf, nullptr, 256, 256, 1024, 1);
      gemm_split<<<dim3(2, 85, 2), blk, 0, stream>>>(
          hbuf, w2s + (size_t)i * 524288, bl2 + i * 256,
          y + ro * 256, y2 + ro * 256, 1024, 512, 256, 0);
    }
    // x = LN(x + y + y2)  (last layer -> d_out; safe: y2 read before write)
    float* dst = (i == NL_ - 1) ? (float*)d_out : x;
    resid_ln3<<<M_, blk, 0, stream>>>(x, y, y2, g2 + i * 256, be2 + i * 256, dst);
    xc = x;
  }
}